// Round 2
// baseline (237.000 us; speedup 1.0000x reference)
//
#include <hip/hip_runtime.h>
#include <math.h>

// Problem constants: B=8, C=64 (HC=32), H=W=256.
// Outputs (concat, fp32): score[8*65536] | out[8*65536*5] | m[8*65536]
// NOTE: hmap (vertical conv) in the reference is dead code: bf[:,:,2] is never
// used (wv=bf[:,:,0]=score, hv=bf[:,:,1]=wmap). We skip it.

__device__ __forceinline__ void insert10(float (&a)[10], float v) {
    if (v > a[9]) {
#pragma unroll
        for (int k = 0; k < 10; ++k) {
            if (v > a[k]) { float t = a[k]; a[k] = v; v = t; }
        }
    }
}

// K1: fused score (64-ch dot) + wmap (5-tap horiz depthwise conv on even
// channels, max over 32 channels).
// R1 restructure: one BLOCK per image row (grid 2048 = 8 blocks/CU-worth of
// work, 4 resident at __launch_bounds__(256,4) -> 16 waves/CU, 4 waves/SIMD —
// 4x the TLP of the old 512-block layout, which was 2 waves/SIMD and
// latency-bound). Each of the 4 waves owns 16 of the 64 channels; partial
// score-sums (add) and conv-maxes (max) are combined via 8 KB of LDS.
// Conv halo via wave shuffles (row boundary == wave boundary, unchanged).
__global__ __launch_bounds__(256, 4) void k_main(
    const float* __restrict__ color,
    const float* __restrict__ w_bbx,
    const float* __restrict__ w_width,
    const float* __restrict__ w_score,
    float* __restrict__ score_out,
    float* __restrict__ wmap_out)
{
    const int tid  = threadIdx.x;
    const int lane = tid & 63;
    const int wid  = tid >> 6;              // 0..3: channel group (wave-uniform)
    const int bid  = blockIdx.x;            // 0..2047
    const int b    = bid >> 8;              // batch
    const int h    = bid & 255;             // row
    const int w0   = lane << 2;             // 0..252

    // scalar-path channel base for weight loads (wid is wave-uniform)
    const int cg = __builtin_amdgcn_readfirstlane(wid) << 4;  // 0,16,32,48

    const float* base = color + ((size_t)b << 22) + ((size_t)h << 8) + (size_t)w0
                              + ((size_t)cg << 16);

    float a0 = 0.f, a1 = 0.f, a2 = 0.f, a3 = 0.f;
    float m0 = -INFINITY, m1 = -INFINITY, m2 = -INFINITY, m3 = -INFINITY;

#pragma unroll
    for (int cc = 0; cc < 16; cc += 2) {
        const float4 v = *reinterpret_cast<const float4*>(base + ((size_t)cc << 16));
        const float4 u = *reinterpret_cast<const float4*>(base + ((size_t)(cc + 1) << 16));
        const int c = cg + cc;
        const float wsc0 = w_score[c];
        const float wsc1 = w_score[c + 1];
        a0 += v.x * wsc0 + u.x * wsc1;
        a1 += v.y * wsc0 + u.y * wsc1;
        a2 += v.z * wsc0 + u.z * wsc1;
        a3 += v.w * wsc0 + u.w * wsc1;

        // wh = color * w_bbx for even channel c; horizontal conv taps t0..t4
        const float wb = w_bbx[c];
        const float ex = v.x * wb, ey = v.y * wb, ez = v.z * wb, ew = v.w * wb;
        float lm2 = __shfl_up(ez, 1);    // pixel w0-2
        float lm1 = __shfl_up(ew, 1);    // pixel w0-1
        float rp1 = __shfl_down(ex, 1);  // pixel w0+4
        float rp2 = __shfl_down(ey, 1);  // pixel w0+5
        if (lane == 0)  { lm2 = 0.f; lm1 = 0.f; }   // zero padding (left)
        if (lane == 63) { rp1 = 0.f; rp2 = 0.f; }   // zero padding (right)

        const int hc = c >> 1;
        const float t0 = w_width[hc * 5 + 0];
        const float t1 = w_width[hc * 5 + 1];
        const float t2 = w_width[hc * 5 + 2];
        const float t3 = w_width[hc * 5 + 3];
        const float t4 = w_width[hc * 5 + 4];

        m0 = fmaxf(m0, lm2 * t0 + lm1 * t1 + ex * t2 + ey * t3 + ez * t4);
        m1 = fmaxf(m1, lm1 * t0 + ex * t1 + ey * t2 + ez * t3 + ew * t4);
        m2 = fmaxf(m2, ex * t0 + ey * t1 + ez * t2 + ew * t3 + rp1 * t4);
        m3 = fmaxf(m3, ey * t0 + ez * t1 + ew * t2 + rp1 * t3 + rp2 * t4);
    }

    // Combine the 4 waves' partials through LDS (8 KB).
    __shared__ float sa[4][256];
    __shared__ float sm[4][256];
    *reinterpret_cast<float4*>(&sa[wid][w0]) = make_float4(a0, a1, a2, a3);
    *reinterpret_cast<float4*>(&sm[wid][w0]) = make_float4(m0, m1, m2, m3);
    __syncthreads();

    // 256 threads -> 256 pixels of this row; coalesced 1-float stores.
    const float s = (sa[0][tid] + sa[1][tid]) + (sa[2][tid] + sa[3][tid]);
    const float m = fmaxf(fmaxf(sm[0][tid], sm[1][tid]), fmaxf(sm[2][tid], sm[3][tid]));
    const size_t o = ((size_t)b << 16) + ((size_t)h << 8) + (size_t)tid;
    score_out[o] = s;
    wmap_out[o]  = m;
}

// K2a: per (batch, slice-of-8192) top-10 of score. 64 blocks = 8 batches x 8
// slices. Register top-10 per thread, then LDS tree-merge using the sorted-
// merge identity c[k] = max(a[k], b[k], max_i min(a[i], b[k-1-i])) (static
// indices only -> no scratch spill).
__global__ __launch_bounds__(256) void k_top_a(
    const float* __restrict__ score, float* __restrict__ lists)
{
    const int tid   = threadIdx.x;
    const int slice = blockIdx.x & 7;
    const int b     = blockIdx.x >> 3;
    const float* p  = score + ((size_t)b << 16) + ((size_t)slice << 13);

    float a[10];
#pragma unroll
    for (int k = 0; k < 10; ++k) a[k] = -INFINITY;
    for (int j = tid; j < 8192; j += 256) insert10(a, p[j]);

    __shared__ float buf[256][11];  // +1 pad: conflict-free
#pragma unroll
    for (int k = 0; k < 10; ++k) buf[tid][k] = a[k];
    __syncthreads();

    for (int n = 128; n >= 1; n >>= 1) {
        if (tid < n) {
            float bb[10];
#pragma unroll
            for (int k = 0; k < 10; ++k) bb[k] = buf[tid + n][k];
            float c[10];
#pragma unroll
            for (int k = 0; k < 10; ++k) {
                float best = fmaxf(a[k], bb[k]);
#pragma unroll
                for (int i = 0; i < k; ++i) best = fmaxf(best, fminf(a[i], bb[k - 1 - i]));
                c[k] = best;
            }
#pragma unroll
            for (int k = 0; k < 10; ++k) { a[k] = c[k]; buf[tid][k] = c[k]; }
        }
        __syncthreads();
    }
    if (tid == 0) {
#pragma unroll
        for (int k = 0; k < 10; ++k) lists[blockIdx.x * 10 + k] = a[k];
    }
}

// K2b: merge the 8 slice-lists per batch -> t[b] = 10th largest score.
__global__ void k_top_b(const float* __restrict__ lists, float* __restrict__ tvals)
{
    const int b = threadIdx.x;
    if (b < 8) {
        float a[10];
#pragma unroll
        for (int k = 0; k < 10; ++k) a[k] = -INFINITY;
        for (int j = 0; j < 80; ++j) insert10(a, lists[b * 80 + j]);
        tvals[b] = a[9];
    }
}

// K3: epilogue. Reads score + wmap (parked in the m-output region), writes
// out[.,5] and m. fp64 for sigmoid/exp/floor/ceil decisions to match the
// numpy reference's rounding behavior; same-thread read-then-overwrite of
// mout[i] is safe.
__global__ __launch_bounds__(256) void k_boxes(
    const float* __restrict__ score,
    const float* __restrict__ tvals,
    float* __restrict__ out5,
    float* __restrict__ mout)
{
    const int i   = blockIdx.x * 256 + threadIdx.x;  // < 524288
    const float sc = score[i];
    const float wm = mout[i];
    const int b   = i >> 16;
    const int pix = i & 65535;
    const float tb = tvals[b];

    const double sd  = 1.0 / (1.0 + exp(-(double)sc));
    const bool  top  = (sc >= tb);  // monotone: top-10 of sigmoid == top-10 of score
    const bool  m    = (top && (sd > 0.6)) || (sd > 0.8);

    const double xg = (double)(pix & 255);
    const double yg = (double)(pix >> 8);
    const double cw = exp((double)sc) * 10.0;  // wv = bf[:,:,0] = score
    const double ch = exp((double)wm) * 10.0;  // hv = bf[:,:,1] = wmap

    double x1 = floor(xg - cw), x2 = ceil(xg + cw);
    double y1 = floor(yg - ch), y2 = ceil(yg + ch);
    if ((x1 < 0.0) || (x2 > 256.0)) {
        const double hw = fmin(256.0 - xg, xg);
        x1 = floor(xg - hw); x2 = ceil(xg + hw);
    }
    if ((y1 < 0.0) || (y2 > 256.0)) {
        const double hh = fmin(256.0 - yg, yg);
        y1 = floor(yg - hh); y2 = ceil(yg + hh);
    }

    const float mf = m ? 1.0f : 0.0f;
    const size_t o = (size_t)i * 5;
    out5[o + 0] = mf * (float)sd;
    out5[o + 1] = mf * (float)x1;
    out5[o + 2] = mf * (float)y1;
    out5[o + 3] = mf * (float)x2;
    out5[o + 4] = mf * (float)y2;
    mout[i] = mf;
}

extern "C" void kernel_launch(void* const* d_in, const int* in_sizes, int n_in,
                              void* d_out, int out_size, void* d_ws, size_t ws_size,
                              hipStream_t stream) {
    // inputs: 0=mask(unused), 1=color, 2=w_bbx, 3=w_width, 4=w_height(dead), 5=w_score
    const float* color   = (const float*)d_in[1];
    const float* w_bbx   = (const float*)d_in[2];
    const float* w_width = (const float*)d_in[3];
    const float* w_score = (const float*)d_in[5];

    float* score_out = (float*)d_out;                       // 524288
    float* out5      = score_out + 524288;                  // 2621440
    float* mout      = score_out + 524288 + 2621440;        // 524288 (holds wmap between K1 and K3)

    float* lists = (float*)d_ws;   // 640 floats
    float* tvals = lists + 640;    // 8 floats

    k_main <<<2048, 256, 0, stream>>>(color, w_bbx, w_width, w_score, score_out, mout);
    k_top_a<<<64,   256, 0, stream>>>(score_out, lists);
    k_top_b<<<1,    64,  0, stream>>>(lists, tvals);
    k_boxes<<<2048, 256, 0, stream>>>(score_out, tvals, out5, mout);
}

// Round 3
// 211.700 us; speedup vs baseline: 1.1195x; 1.1195x over previous
//
#include <hip/hip_runtime.h>
#include <math.h>

// Problem constants: B=8, C=64 (HC=32), H=W=256.
// Outputs (concat, fp32): score[8*65536] | out[8*65536*5] | m[8*65536]
// NOTE: hmap (vertical conv) in the reference is dead code: bf[:,:,2] is never
// used (wv=bf[:,:,0]=score, hv=bf[:,:,1]=wmap). We skip it.
//
// R2: pipeline collapsed 4 -> 3 kernels. k_main now folds the per-row top-10
// (shfl_xor butterfly merge of sorted-10 lists); k_reduce (8 blocks) merges
// 256 row-lists per batch -> tvals. Purpose: discriminate "harness fill floor"
// (dur_us stays ~237) vs "launch/dispatch overhead" (dur_us drops).

// Sorted-descending 10-list merge: c[k] = max(a[k], b[k], max_i<k min(a[i], b[k-1-i])).
// Static indices only -> stays in registers.
__device__ __forceinline__ void merge10(float (&a)[10], const float (&b)[10]) {
    float c[10];
#pragma unroll
    for (int k = 0; k < 10; ++k) {
        float best = fmaxf(a[k], b[k]);
#pragma unroll
        for (int i = 0; i < k; ++i) best = fmaxf(best, fminf(a[i], b[k - 1 - i]));
        c[k] = best;
    }
#pragma unroll
    for (int k = 0; k < 10; ++k) a[k] = c[k];
}

__device__ __forceinline__ void insert10(float (&a)[10], float v) {
    if (v > a[9]) {
#pragma unroll
        for (int k = 0; k < 10; ++k) {
            if (v > a[k]) { float t = a[k]; a[k] = v; v = t; }
        }
    }
}

// K1: fused score (64-ch dot) + wmap (5-tap horiz depthwise conv on even
// channels, max over 32 channels) + per-row top-10 of score.
// One block per image row; 4 waves x 16 channels; partials combined via LDS.
// Conv halo via wave shuffles (row boundary == wave boundary).
__global__ __launch_bounds__(256, 4) void k_main(
    const float* __restrict__ color,
    const float* __restrict__ w_bbx,
    const float* __restrict__ w_width,
    const float* __restrict__ w_score,
    float* __restrict__ score_out,
    float* __restrict__ wmap_out,
    float* __restrict__ lists)          // [2048][10] per-row sorted top-10
{
    const int tid  = threadIdx.x;
    const int lane = tid & 63;
    const int wid  = tid >> 6;              // 0..3: channel group (wave-uniform)
    const int bid  = blockIdx.x;            // 0..2047
    const int b    = bid >> 8;              // batch
    const int h    = bid & 255;             // row
    const int w0   = lane << 2;             // 0..252

    const int cg = __builtin_amdgcn_readfirstlane(wid) << 4;  // 0,16,32,48

    const float* base = color + ((size_t)b << 22) + ((size_t)h << 8) + (size_t)w0
                              + ((size_t)cg << 16);

    float a0 = 0.f, a1 = 0.f, a2 = 0.f, a3 = 0.f;
    float m0 = -INFINITY, m1 = -INFINITY, m2 = -INFINITY, m3 = -INFINITY;

#pragma unroll
    for (int cc = 0; cc < 16; cc += 2) {
        const float4 v = *reinterpret_cast<const float4*>(base + ((size_t)cc << 16));
        const float4 u = *reinterpret_cast<const float4*>(base + ((size_t)(cc + 1) << 16));
        const int c = cg + cc;
        const float wsc0 = w_score[c];
        const float wsc1 = w_score[c + 1];
        a0 += v.x * wsc0 + u.x * wsc1;
        a1 += v.y * wsc0 + u.y * wsc1;
        a2 += v.z * wsc0 + u.z * wsc1;
        a3 += v.w * wsc0 + u.w * wsc1;

        const float wb = w_bbx[c];
        const float ex = v.x * wb, ey = v.y * wb, ez = v.z * wb, ew = v.w * wb;
        float lm2 = __shfl_up(ez, 1);    // pixel w0-2
        float lm1 = __shfl_up(ew, 1);    // pixel w0-1
        float rp1 = __shfl_down(ex, 1);  // pixel w0+4
        float rp2 = __shfl_down(ey, 1);  // pixel w0+5
        if (lane == 0)  { lm2 = 0.f; lm1 = 0.f; }   // zero padding (left)
        if (lane == 63) { rp1 = 0.f; rp2 = 0.f; }   // zero padding (right)

        const int hc = c >> 1;
        const float t0 = w_width[hc * 5 + 0];
        const float t1 = w_width[hc * 5 + 1];
        const float t2 = w_width[hc * 5 + 2];
        const float t3 = w_width[hc * 5 + 3];
        const float t4 = w_width[hc * 5 + 4];

        m0 = fmaxf(m0, lm2 * t0 + lm1 * t1 + ex * t2 + ey * t3 + ez * t4);
        m1 = fmaxf(m1, lm1 * t0 + ex * t1 + ey * t2 + ez * t3 + ew * t4);
        m2 = fmaxf(m2, ex * t0 + ey * t1 + ez * t2 + ew * t3 + rp1 * t4);
        m3 = fmaxf(m3, ey * t0 + ez * t1 + ew * t2 + rp1 * t3 + rp2 * t4);
    }

    // Combine the 4 waves' partials through LDS (8 KB).
    __shared__ float sa[4][256];
    __shared__ float sm[4][256];
    *reinterpret_cast<float4*>(&sa[wid][w0]) = make_float4(a0, a1, a2, a3);
    *reinterpret_cast<float4*>(&sm[wid][w0]) = make_float4(m0, m1, m2, m3);
    __syncthreads();

    // 256 threads -> 256 pixels of this row; coalesced stores.
    const float s = (sa[0][tid] + sa[1][tid]) + (sa[2][tid] + sa[3][tid]);
    const float m = fmaxf(fmaxf(sm[0][tid], sm[1][tid]), fmaxf(sm[2][tid], sm[3][tid]));
    const size_t o = ((size_t)b << 16) + ((size_t)h << 8) + (size_t)tid;
    score_out[o] = s;
    wmap_out[o]  = m;

    // ---- per-row top-10 (of the 256 scores this block just produced) ----
    // Each wave reduces its own 64 values: per-lane 1-value list, 6 butterfly
    // rounds of sorted-10 merges -> all lanes hold the wave's top-10.
    float t10[10];
    t10[0] = s;
#pragma unroll
    for (int k = 1; k < 10; ++k) t10[k] = -INFINITY;

#pragma unroll
    for (int off = 1; off < 64; off <<= 1) {
        float b10[10];
#pragma unroll
        for (int k = 0; k < 10; ++k) b10[k] = __shfl_xor(t10[k], off);
        merge10(t10, b10);
    }

    __shared__ float wl[4][10];
    if (lane == 0) {
#pragma unroll
        for (int k = 0; k < 10; ++k) wl[wid][k] = t10[k];
    }
    __syncthreads();

    if (tid == 0) {
        float fa[10], fb[10];
#pragma unroll
        for (int k = 0; k < 10; ++k) fa[k] = wl[0][k];
#pragma unroll
        for (int k = 0; k < 10; ++k) fb[k] = wl[1][k];
        merge10(fa, fb);
#pragma unroll
        for (int k = 0; k < 10; ++k) fb[k] = wl[2][k];
        merge10(fa, fb);
#pragma unroll
        for (int k = 0; k < 10; ++k) fb[k] = wl[3][k];
        merge10(fa, fb);
#pragma unroll
        for (int k = 0; k < 10; ++k) lists[bid * 10 + k] = fa[k];
    }
}

// K2: one block per batch; merge 256 per-row sorted-10 lists -> tvals[b]
// = 10th largest score of the batch. Thread t owns row t's list; LDS tree.
__global__ __launch_bounds__(256) void k_reduce(
    const float* __restrict__ lists, float* __restrict__ tvals)
{
    const int tid = threadIdx.x;
    const int b   = blockIdx.x;            // 0..7
    const float* p = lists + (size_t)b * 2560 + (size_t)tid * 10;

    float a[10];
#pragma unroll
    for (int k = 0; k < 10; ++k) a[k] = p[k];   // sorted descending already

    __shared__ float buf[256][11];  // +1 pad: conflict-free
#pragma unroll
    for (int k = 0; k < 10; ++k) buf[tid][k] = a[k];
    __syncthreads();

    for (int n = 128; n >= 1; n >>= 1) {
        if (tid < n) {
            float bb[10];
#pragma unroll
            for (int k = 0; k < 10; ++k) bb[k] = buf[tid + n][k];
            merge10(a, bb);
#pragma unroll
            for (int k = 0; k < 10; ++k) buf[tid][k] = a[k];
        }
        __syncthreads();
    }
    if (tid == 0) tvals[b] = a[9];
}

// K3: epilogue. Reads score + wmap (parked in the m-output region), writes
// out[.,5] and m. fp64 for sigmoid/exp/floor/ceil decisions to match the
// numpy reference's rounding behavior; same-thread read-then-overwrite of
// mout[i] is safe.
__global__ __launch_bounds__(256) void k_boxes(
    const float* __restrict__ score,
    const float* __restrict__ tvals,
    float* __restrict__ out5,
    float* __restrict__ mout)
{
    const int i   = blockIdx.x * 256 + threadIdx.x;  // < 524288
    const float sc = score[i];
    const float wm = mout[i];
    const int b   = i >> 16;
    const int pix = i & 65535;
    const float tb = tvals[b];

    const double sd  = 1.0 / (1.0 + exp(-(double)sc));
    const bool  top  = (sc >= tb);  // monotone: top-10 of sigmoid == top-10 of score
    const bool  m    = (top && (sd > 0.6)) || (sd > 0.8);

    const double xg = (double)(pix & 255);
    const double yg = (double)(pix >> 8);
    const double cw = exp((double)sc) * 10.0;  // wv = bf[:,:,0] = score
    const double ch = exp((double)wm) * 10.0;  // hv = bf[:,:,1] = wmap

    double x1 = floor(xg - cw), x2 = ceil(xg + cw);
    double y1 = floor(yg - ch), y2 = ceil(yg + ch);
    if ((x1 < 0.0) || (x2 > 256.0)) {
        const double hw = fmin(256.0 - xg, xg);
        x1 = floor(xg - hw); x2 = ceil(xg + hw);
    }
    if ((y1 < 0.0) || (y2 > 256.0)) {
        const double hh = fmin(256.0 - yg, yg);
        y1 = floor(yg - hh); y2 = ceil(yg + hh);
    }

    const float mf = m ? 1.0f : 0.0f;
    const size_t o = (size_t)i * 5;
    out5[o + 0] = mf * (float)sd;
    out5[o + 1] = mf * (float)x1;
    out5[o + 2] = mf * (float)y1;
    out5[o + 3] = mf * (float)x2;
    out5[o + 4] = mf * (float)y2;
    mout[i] = mf;
}

extern "C" void kernel_launch(void* const* d_in, const int* in_sizes, int n_in,
                              void* d_out, int out_size, void* d_ws, size_t ws_size,
                              hipStream_t stream) {
    // inputs: 0=mask(unused), 1=color, 2=w_bbx, 3=w_width, 4=w_height(dead), 5=w_score
    const float* color   = (const float*)d_in[1];
    const float* w_bbx   = (const float*)d_in[2];
    const float* w_width = (const float*)d_in[3];
    const float* w_score = (const float*)d_in[5];

    float* score_out = (float*)d_out;                       // 524288
    float* out5      = score_out + 524288;                  // 2621440
    float* mout      = score_out + 524288 + 2621440;        // 524288 (holds wmap between K1 and K3)

    float* lists = (float*)d_ws;   // 2048*10 floats
    float* tvals = lists + 20480;  // 8 floats

    k_main  <<<2048, 256, 0, stream>>>(color, w_bbx, w_width, w_score, score_out, mout, lists);
    k_reduce<<<8,    256, 0, stream>>>(lists, tvals);
    k_boxes <<<2048, 256, 0, stream>>>(score_out, tvals, out5, mout);
}